// Round 9
// baseline (141.648 us; speedup 1.0000x reference)
//
#include <hip/hip_runtime.h>
#include <hip/hip_bf16.h>

typedef unsigned short u16;
typedef unsigned int u32;
typedef __attribute__((ext_vector_type(8))) short bf16x8;
typedef __attribute__((ext_vector_type(4))) float floatx4;
typedef __attribute__((ext_vector_type(2))) float f32x2;

__device__ __forceinline__ float bflo(u32 u){ union{u32 i; float f;}v; v.i=u<<16; return v.f; }
__device__ __forceinline__ float bfhi(u32 u){ union{u32 i; float f;}v; v.i=u&0xFFFF0000u; return v.f; }
// unpack two bf16 in a u32 -> f32x2 (2 VALU: v_lshlrev + v_and)
__device__ __forceinline__ f32x2 up2(u32 u){
    union{u32 i; float f;} lo, hi; lo.i = u << 16; hi.i = u & 0xFFFF0000u;
    f32x2 r; r.x = lo.f; r.y = hi.f; return r;
}
__device__ __forceinline__ u16 f2bf(float f){
    union{float f;u32 i;}v; v.f=f; u32 r=v.i+0x7FFFu+((v.i>>16)&1u); return (u16)(r>>16);
}
__device__ __forceinline__ u32 pkbf(float a, float b){
    union { __hip_bfloat162 h; u32 u; } cv;
    cv.h = __float22bfloat162_rn(float2{a, b});
    return cv.u;
}

#define DD 512
#define NTOK 128

// ---------------------------------------------------------------------------
// prep_k: grid (16,8,3), 512 thr.  (R5-proven, unchanged)
// ---------------------------------------------------------------------------
__global__ __launch_bounds__(512) void prep_k(
    const float* __restrict__ features, const float* __restrict__ W1,
    const float* __restrict__ W2, const float* __restrict__ b1,
    u16* __restrict__ Hf1b, u16* __restrict__ Hf2, u16* __restrict__ W2T)
{
    const int z = blockIdx.z;
    const int tid = threadIdx.x;

    if (z == 2) {   // W2 transpose
        __shared__ u16 tile[32][33];
        const int tx = tid & 31, ty = tid >> 5;      // ty 0..15
        const int r0 = blockIdx.x * 32, c0 = blockIdx.y * 32;
#pragma unroll
        for (int i = 0; i < 2; ++i) {
            int r = ty + i * 16;
            tile[r][tx] = f2bf(W2[(size_t)(r0 + r) * 256 + (c0 + tx)]);
        }
        __syncthreads();
#pragma unroll
        for (int i = 0; i < 2; ++i) {
            int c = ty + i * 16;
            W2T[(size_t)(c0 + c) * 512 + (r0 + tx)] = tile[tx][c];
        }
        return;
    }

    const int bM = blockIdx.x, bN = blockIdx.y;
    u16* outp = z ? Hf2 : Hf1b;
    __shared__ __align__(16) u16 At[64 * 64];
    __shared__ __align__(16) u16 Btl[64 * 64];
    const int wid = tid >> 6, lane = tid & 63, lrow = lane & 15, quad = lane >> 4;
    const int wm = wid >> 1, wn = wid & 1;

    floatx4 acc[2];
    acc[0] = (floatx4)(0.0f); acc[1] = (floatx4)(0.0f);

    const int m = tid >> 3, seg = tid & 7, sw = m & 7;      // A staging map
    const int kr = tid >> 3, csB = tid & 7;                 // B staging map

    for (int kc = 0; kc < 8; ++kc) {
        const int k0 = kc * 64;
        {   // stage A: 8 fp32 -> 8 bf16, one uint4, XOR-swizzled
            const float4* src = (const float4*)(features + (size_t)(bM * 64 + m) * DD + k0 + seg * 8);
            float4 f0 = src[0], f1 = src[1];
            *(uint4*)(At + m * 64 + ((seg ^ sw) << 3)) =
                make_uint4(pkbf(f0.x, f0.y), pkbf(f0.z, f0.w), pkbf(f1.x, f1.y), pkbf(f1.z, f1.w));
        }
        {   // stage B from W1 rows (transpose-in-write, swizzled scalar b16)
            const float4* src = (const float4*)(W1 + (size_t)(z * 512 + k0 + kr) * DD + bN * 64 + csB * 8);
            float4 g0 = src[0], g1 = src[1];
            float f[8] = { g0.x, g0.y, g0.z, g0.w, g1.x, g1.y, g1.z, g1.w };
            const int chunkB = (kr >> 3), offB = kr & 7;
#pragma unroll
            for (int i = 0; i < 8; ++i) {
                int c = csB * 8 + i;                        // c & 7 == i
                Btl[c * 64 + ((chunkB ^ i) << 3) + offB] = f2bf(f[i]);
            }
        }
        __syncthreads();
#pragma unroll
        for (int ks = 0; ks < 2; ++ks) {
            const int ch = ks * 4 + quad;
            int r = wm * 16 + lrow;
            bf16x8 afr = *(const bf16x8*)(At + r * 64 + ((ch ^ (r & 7)) << 3));
#pragma unroll
            for (int j = 0; j < 2; ++j) {
                int c = wn * 32 + j * 16 + lrow;
                bf16x8 bfr = *(const bf16x8*)(Btl + c * 64 + ((ch ^ (c & 7)) << 3));
                acc[j] = __builtin_amdgcn_mfma_f32_16x16x32_bf16(afr, bfr, acc[j], 0, 0, 0);
            }
        }
        __syncthreads();
    }
#pragma unroll
    for (int j = 0; j < 2; ++j) {
        int col = bN * 64 + wn * 32 + j * 16 + lrow;
        float bb = z ? 0.0f : b1[col];
#pragma unroll
        for (int r = 0; r < 4; ++r) {
            int row = bM * 64 + wm * 16 + quad * 4 + r;
            outp[(size_t)row * DD + col] = f2bf(acc[j][r] + bb);
        }
    }
}

// ---------------------------------------------------------------------------
// Fused main — R8 frame (VGPR=64, 2 blocks/CU, XCD-pinned grid) with:
//  * packed-f32 (v_pk_fma_f32) H-build math (~28% fewer VALU ops, bit-identical)
//  * B-staging global loads issued before the A-phase (latency slack)
//  * __launch_bounds__(512,4) pins 4 waves/SIMD (guards the R6/R7 VGPR cliff)
// ---------------------------------------------------------------------------
__global__ __launch_bounds__(512, 4) void fused_main(
    const u16* __restrict__ Hf1b, const u16* __restrict__ Hf2,
    const u16* __restrict__ W2T, const float* __restrict__ W1,
    const float* __restrict__ b2, const float* __restrict__ W3,
    const float* __restrict__ b3, const float* __restrict__ positions,
    float* __restrict__ out)
{
    const int b = blockIdx.x, n = blockIdx.y;     // b fastest -> XCD = b
    const int tid = threadIdx.x;
    const int base_bn = b * NTOK + n;
    const int wid = tid >> 6, lane = tid & 63, lrow = lane & 15, quad = lane >> 4;

    __shared__ __align__(16) u16 c0b[DD], c1b[DD], s1b[DD];  // bf16 coefs, 3 KB
    __shared__ __align__(16) u16 w3t[16 * 264];              // W3^T padded, 8.25 KB
    __shared__ __align__(16) char mbuf[49152];   // Atile 16K + Btile 32K | gh 34K
    u16* Atile = (u16*)mbuf;                     // [128][64] swizzled
    u16* Btile = (u16*)(mbuf + 16384);           // [256][64] swizzled
    u16* gh    = (u16*)mbuf;                     // [128][136] epilogue

    // ---- phase 0 ----
    {
        int k = tid;  // 512 threads == DD
        c0b[k] = f2bf(W1[(size_t)1024 * DD + k]);
        c1b[k] = f2bf(W1[(size_t)1025 * DD + k]);
        s1b[k] = Hf1b[(size_t)base_bn * DD + k];   // b1 already folded
    }
    {   // w3t: W3 (256x4 fp32) transposed, padded to 16 cols, bf16
        int c = tid & 15, kb2 = tid >> 4;          // kb2 0..31
        int k0w = kb2 * 8;
        u32 wv[4];
#pragma unroll
        for (int p = 0; p < 4; ++p) {
            int ka = k0w + p * 2;
            u16 va = (c < 4) ? f2bf(W3[ka * 4 + c])       : (u16)0;
            u16 vb = (c < 4) ? f2bf(W3[(ka + 1) * 4 + c]) : (u16)0;
            wv[p] = (u32)va | ((u32)vb << 16);
        }
        *(uint2*)(w3t + c * 264 + k0w)     = make_uint2(wv[0], wv[1]);
        *(uint2*)(w3t + c * 264 + k0w + 4) = make_uint2(wv[2], wv[3]);
    }
    const int mrow = tid >> 2, seg = tid & 3, swA = mrow & 7;
    f32x2 px2, py2;
    {
        float pnx = positions[(size_t)base_bn * 2 + 0];
        float pny = positions[(size_t)base_bn * 2 + 1];
        float px = pnx - positions[(size_t)(b * NTOK + mrow) * 2 + 0];
        float py = pny - positions[(size_t)(b * NTOK + mrow) * 2 + 1];
        px2.x = px; px2.y = px; py2.x = py; py2.y = py;
    }
    __syncthreads();

    const int wm = wid >> 2, wn = wid & 3;       // main GEMM 2x4 wave grid
    floatx4 acc[4][4];
#pragma unroll
    for (int i = 0; i < 4; ++i)
#pragma unroll
        for (int j = 0; j < 4; ++j) acc[i][j] = (floatx4)(0.0f);

    const u16* hf2p = Hf2 + (size_t)(b * NTOK + mrow) * DD;
    const int cB = tid >> 1, sgB = tid & 1, swB = cB & 7;   // B staging map

    // ---- K loop ----
    for (int kc = 0; kc < 8; ++kc) {
        const int k0 = kc * 64;
        // stage B global loads FIRST (L2-resident W2T; issue early for slack)
        const uint4* bsrc = (const uint4*)(W2T + (size_t)cB * DD + k0 + sgB * 32);
        uint4 bld0 = bsrc[0], bld1 = bsrc[1], bld2 = bsrc[2], bld3 = bsrc[3];

        const int kb = k0 + seg * 16;
        {   // stage A: h = relu(hf2 + s1 + px*c0 + py*c1), packed-f32 math
            uint4 hv = *(const uint4*)(hf2p + kb);
            uint4 hw = *(const uint4*)(hf2p + kb + 8);
            uint4 sv = *(const uint4*)(s1b + kb);
            uint4 sw2 = *(const uint4*)(s1b + kb + 8);
            uint4 av = *(const uint4*)(c0b + kb);
            uint4 aw = *(const uint4*)(c0b + kb + 8);
            uint4 bv = *(const uint4*)(c1b + kb);
            uint4 bw = *(const uint4*)(c1b + kb + 8);
            auto hp = [&](u32 h, u32 s, u32 ca, u32 cb) -> u32 {
                f32x2 v = up2(h) + up2(s);          // v_pk_add_f32
                v += px2 * up2(ca);                 // v_pk_fma_f32
                v += py2 * up2(cb);                 // v_pk_fma_f32
                v.x = fmaxf(v.x, 0.0f); v.y = fmaxf(v.y, 0.0f);  // v_pk_max_f32
                return pkbf(v.x, v.y);              // v_cvt_pk_bf16_f32
            };
            uint4 o0 = make_uint4(hp(hv.x, sv.x, av.x, bv.x), hp(hv.y, sv.y, av.y, bv.y),
                                  hp(hv.z, sv.z, av.z, bv.z), hp(hv.w, sv.w, av.w, bv.w));
            uint4 o1 = make_uint4(hp(hw.x, sw2.x, aw.x, bw.x), hp(hw.y, sw2.y, aw.y, bw.y),
                                  hp(hw.z, sw2.z, aw.z, bw.z), hp(hw.w, sw2.w, aw.w, bw.w));
            *(uint4*)(Atile + mrow * 64 + (((seg * 2    ) ^ swA) << 3)) = o0;
            *(uint4*)(Atile + mrow * 64 + (((seg * 2 + 1) ^ swA) << 3)) = o1;
        }
        {   // stage B writes (data already in flight)
            *(uint4*)(Btile + cB * 64 + (((sgB * 4 + 0) ^ swB) << 3)) = bld0;
            *(uint4*)(Btile + cB * 64 + (((sgB * 4 + 1) ^ swB) << 3)) = bld1;
            *(uint4*)(Btile + cB * 64 + (((sgB * 4 + 2) ^ swB) << 3)) = bld2;
            *(uint4*)(Btile + cB * 64 + (((sgB * 4 + 3) ^ swB) << 3)) = bld3;
        }
        __syncthreads();
#pragma unroll
        for (int ks = 0; ks < 2; ++ks) {
            const int ch = ks * 4 + quad;
            bf16x8 afr[4], bfr[4];
#pragma unroll
            for (int i = 0; i < 4; ++i) {
                int r = wm * 64 + i * 16 + lrow;
                afr[i] = *(const bf16x8*)(Atile + r * 64 + ((ch ^ (r & 7)) << 3));
            }
#pragma unroll
            for (int j = 0; j < 4; ++j) {
                int c = wn * 64 + j * 16 + lrow;
                bfr[j] = *(const bf16x8*)(Btile + c * 64 + ((ch ^ (c & 7)) << 3));
            }
#pragma unroll
            for (int i = 0; i < 4; ++i)
#pragma unroll
                for (int j = 0; j < 4; ++j)
                    acc[i][j] = __builtin_amdgcn_mfma_f32_16x16x32_bf16(afr[i], bfr[j], acc[i][j], 0, 0, 0);
        }
        __syncthreads();
    }

    // ---- epilogue: relu(acc+b2) -> gh bf16 halves -> layer-3 MFMA ----
    float b2v[4];
#pragma unroll
    for (int j = 0; j < 4; ++j) b2v[j] = b2[wn * 64 + j * 16 + lrow];

    const int smrow = wid * 16;                  // per-wave epilogue row block
    floatx4 acc3 = (floatx4)(0.0f);
#pragma unroll
    for (int half = 0; half < 2; ++half) {
        __syncthreads();
        if ((wn >> 1) == half) {
#pragma unroll
            for (int i = 0; i < 4; ++i)
#pragma unroll
                for (int j = 0; j < 4; ++j)
#pragma unroll
                    for (int r = 0; r < 4; ++r) {
                        int row = wm * 64 + i * 16 + quad * 4 + r;
                        int col = (wn & 1) * 64 + j * 16 + lrow;
                        gh[row * 136 + col] = f2bf(fmaxf(acc[i][j][r] + b2v[j], 0.0f));
                    }
        }
        __syncthreads();
#pragma unroll
        for (int ks = 0; ks < 4; ++ks) {
            bf16x8 gfrag = *(const bf16x8*)(gh + (smrow + lrow) * 136 + ks * 32 + quad * 8);
            bf16x8 wfrag = *(const bf16x8*)(w3t + lrow * 264 + half * 128 + ks * 32 + quad * 8);
            acc3 = __builtin_amdgcn_mfma_f32_16x16x32_bf16(gfrag, wfrag, acc3, 0, 0, 0);
        }
    }
    if (lrow < 4) {
        float bo = b3[lrow];
#pragma unroll
        for (int r = 0; r < 4; ++r) {
            int row = smrow + quad * 4 + r;
            out[(size_t)base_bn * 512 + row * 4 + lrow] = acc3[r] + bo;
        }
    }
}

// ---------------------------------------------------------------------------
extern "C" void kernel_launch(void* const* d_in, const int* in_sizes, int n_in,
                              void* d_out, int out_size, void* d_ws, size_t ws_size,
                              hipStream_t stream)
{
    const float* features  = (const float*)d_in[0];
    const float* positions = (const float*)d_in[1];
    const float* W1 = (const float*)d_in[2];
    const float* b1 = (const float*)d_in[3];
    const float* W2 = (const float*)d_in[4];
    const float* b2 = (const float*)d_in[5];
    const float* W3 = (const float*)d_in[6];
    const float* b3 = (const float*)d_in[7];
    float* out = (float*)d_out;

    char* ws = (char*)d_ws;
    u16* W2T  = (u16*)(ws);                 // 256*512*2 = 262144 B
    u16* Hf1b = (u16*)(ws + 262144);        // 1048576 B
    u16* Hf2  = (u16*)(ws + 1310720);       // 1048576 B (total 2.25 MB)

    prep_k<<<dim3(16, 8, 3), 512, 0, stream>>>(features, W1, W2, b1, Hf1b, Hf2, W2T);
    fused_main<<<dim3(8, 128), 512, 0, stream>>>(Hf1b, Hf2, W2T, W1, b2, W3, b3,
                                                 positions, out);
}

// Round 10
// 131.878 us; speedup vs baseline: 1.0741x; 1.0741x over previous
//
#include <hip/hip_runtime.h>
#include <hip/hip_bf16.h>

typedef unsigned short u16;
typedef unsigned int u32;
typedef __attribute__((ext_vector_type(8))) short bf16x8;
typedef __attribute__((ext_vector_type(4))) float floatx4;
typedef __attribute__((ext_vector_type(2))) float f32x2;

__device__ __forceinline__ float bflo(u32 u){ union{u32 i; float f;}v; v.i=u<<16; return v.f; }
__device__ __forceinline__ float bfhi(u32 u){ union{u32 i; float f;}v; v.i=u&0xFFFF0000u; return v.f; }
// unpack two bf16 in a u32 -> f32x2
__device__ __forceinline__ f32x2 up2(u32 u){
    union{u32 i; float f;} lo, hi; lo.i = u << 16; hi.i = u & 0xFFFF0000u;
    f32x2 r; r.x = lo.f; r.y = hi.f; return r;
}
__device__ __forceinline__ u16 f2bf(float f){
    union{float f;u32 i;}v; v.f=f; u32 r=v.i+0x7FFFu+((v.i>>16)&1u); return (u16)(r>>16);
}
__device__ __forceinline__ u32 pkbf(float a, float b){
    union { __hip_bfloat162 h; u32 u; } cv;
    cv.h = __float22bfloat162_rn(float2{a, b});
    return cv.u;
}

#define DD 512
#define NTOK 128

// ---------------------------------------------------------------------------
// prep_k: grid (16,8,3), 512 thr.  (R5-proven, unchanged)
// ---------------------------------------------------------------------------
__global__ __launch_bounds__(512) void prep_k(
    const float* __restrict__ features, const float* __restrict__ W1,
    const float* __restrict__ W2, const float* __restrict__ b1,
    u16* __restrict__ Hf1b, u16* __restrict__ Hf2, u16* __restrict__ W2T)
{
    const int z = blockIdx.z;
    const int tid = threadIdx.x;

    if (z == 2) {   // W2 transpose
        __shared__ u16 tile[32][33];
        const int tx = tid & 31, ty = tid >> 5;      // ty 0..15
        const int r0 = blockIdx.x * 32, c0 = blockIdx.y * 32;
#pragma unroll
        for (int i = 0; i < 2; ++i) {
            int r = ty + i * 16;
            tile[r][tx] = f2bf(W2[(size_t)(r0 + r) * 256 + (c0 + tx)]);
        }
        __syncthreads();
#pragma unroll
        for (int i = 0; i < 2; ++i) {
            int c = ty + i * 16;
            W2T[(size_t)(c0 + c) * 512 + (r0 + tx)] = tile[tx][c];
        }
        return;
    }

    const int bM = blockIdx.x, bN = blockIdx.y;
    u16* outp = z ? Hf2 : Hf1b;
    __shared__ __align__(16) u16 At[64 * 64];
    __shared__ __align__(16) u16 Btl[64 * 64];
    const int wid = tid >> 6, lane = tid & 63, lrow = lane & 15, quad = lane >> 4;
    const int wm = wid >> 1, wn = wid & 1;

    floatx4 acc[2];
    acc[0] = (floatx4)(0.0f); acc[1] = (floatx4)(0.0f);

    const int m = tid >> 3, seg = tid & 7, sw = m & 7;      // A staging map
    const int kr = tid >> 3, csB = tid & 7;                 // B staging map

    for (int kc = 0; kc < 8; ++kc) {
        const int k0 = kc * 64;
        {   // stage A: 8 fp32 -> 8 bf16, one uint4, XOR-swizzled
            const float4* src = (const float4*)(features + (size_t)(bM * 64 + m) * DD + k0 + seg * 8);
            float4 f0 = src[0], f1 = src[1];
            *(uint4*)(At + m * 64 + ((seg ^ sw) << 3)) =
                make_uint4(pkbf(f0.x, f0.y), pkbf(f0.z, f0.w), pkbf(f1.x, f1.y), pkbf(f1.z, f1.w));
        }
        {   // stage B from W1 rows (transpose-in-write, swizzled scalar b16)
            const float4* src = (const float4*)(W1 + (size_t)(z * 512 + k0 + kr) * DD + bN * 64 + csB * 8);
            float4 g0 = src[0], g1 = src[1];
            float f[8] = { g0.x, g0.y, g0.z, g0.w, g1.x, g1.y, g1.z, g1.w };
            const int chunkB = (kr >> 3), offB = kr & 7;
#pragma unroll
            for (int i = 0; i < 8; ++i) {
                int c = csB * 8 + i;                        // c & 7 == i
                Btl[c * 64 + ((chunkB ^ i) << 3) + offB] = f2bf(f[i]);
            }
        }
        __syncthreads();
#pragma unroll
        for (int ks = 0; ks < 2; ++ks) {
            const int ch = ks * 4 + quad;
            int r = wm * 16 + lrow;
            bf16x8 afr = *(const bf16x8*)(At + r * 64 + ((ch ^ (r & 7)) << 3));
#pragma unroll
            for (int j = 0; j < 2; ++j) {
                int c = wn * 32 + j * 16 + lrow;
                bf16x8 bfr = *(const bf16x8*)(Btl + c * 64 + ((ch ^ (c & 7)) << 3));
                acc[j] = __builtin_amdgcn_mfma_f32_16x16x32_bf16(afr, bfr, acc[j], 0, 0, 0);
            }
        }
        __syncthreads();
    }
#pragma unroll
    for (int j = 0; j < 2; ++j) {
        int col = bN * 64 + wn * 32 + j * 16 + lrow;
        float bb = z ? 0.0f : b1[col];
#pragma unroll
        for (int r = 0; r < 4; ++r) {
            int row = bM * 64 + wm * 16 + quad * 4 + r;
            outp[(size_t)row * DD + col] = f2bf(acc[j][r] + bb);
        }
    }
}

// ---------------------------------------------------------------------------
// Fused main — R8 frame VERBATIM (VGPR=64, 2 blocks/CU, XCD-pinned grid,
// B staged load+store interleaved, plain launch_bounds) with ONE change:
// packed-f32 (v_pk_*) H-build math. R9 taught: no early B loads, no
// min-waves pin (that combo spilled to scratch: WRITE_SIZE 2->20 MB).
// ---------------------------------------------------------------------------
__global__ __launch_bounds__(512) void fused_main(
    const u16* __restrict__ Hf1b, const u16* __restrict__ Hf2,
    const u16* __restrict__ W2T, const float* __restrict__ W1,
    const float* __restrict__ b2, const float* __restrict__ W3,
    const float* __restrict__ b3, const float* __restrict__ positions,
    float* __restrict__ out)
{
    const int b = blockIdx.x, n = blockIdx.y;     // b fastest -> XCD = b
    const int tid = threadIdx.x;
    const int base_bn = b * NTOK + n;
    const int wid = tid >> 6, lane = tid & 63, lrow = lane & 15, quad = lane >> 4;

    __shared__ __align__(16) u16 c0b[DD], c1b[DD], s1b[DD];  // bf16 coefs, 3 KB
    __shared__ __align__(16) u16 w3t[16 * 264];              // W3^T padded, 8.25 KB
    __shared__ __align__(16) char mbuf[49152];   // Atile 16K + Btile 32K | gh 34K
    u16* Atile = (u16*)mbuf;                     // [128][64] swizzled
    u16* Btile = (u16*)(mbuf + 16384);           // [256][64] swizzled
    u16* gh    = (u16*)mbuf;                     // [128][136] epilogue

    // ---- phase 0 ----
    {
        int k = tid;  // 512 threads == DD
        c0b[k] = f2bf(W1[(size_t)1024 * DD + k]);
        c1b[k] = f2bf(W1[(size_t)1025 * DD + k]);
        s1b[k] = Hf1b[(size_t)base_bn * DD + k];   // b1 already folded
    }
    {   // w3t: W3 (256x4 fp32) transposed, padded to 16 cols, bf16
        int c = tid & 15, kb2 = tid >> 4;          // kb2 0..31
        int k0w = kb2 * 8;
        u32 wv[4];
#pragma unroll
        for (int p = 0; p < 4; ++p) {
            int ka = k0w + p * 2;
            u16 va = (c < 4) ? f2bf(W3[ka * 4 + c])       : (u16)0;
            u16 vb = (c < 4) ? f2bf(W3[(ka + 1) * 4 + c]) : (u16)0;
            wv[p] = (u32)va | ((u32)vb << 16);
        }
        *(uint2*)(w3t + c * 264 + k0w)     = make_uint2(wv[0], wv[1]);
        *(uint2*)(w3t + c * 264 + k0w + 4) = make_uint2(wv[2], wv[3]);
    }
    const int mrow = tid >> 2, seg = tid & 3, swA = mrow & 7;
    f32x2 px2, py2;
    {
        float pnx = positions[(size_t)base_bn * 2 + 0];
        float pny = positions[(size_t)base_bn * 2 + 1];
        float px = pnx - positions[(size_t)(b * NTOK + mrow) * 2 + 0];
        float py = pny - positions[(size_t)(b * NTOK + mrow) * 2 + 1];
        px2.x = px; px2.y = px; py2.x = py; py2.y = py;
    }
    __syncthreads();

    const int wm = wid >> 2, wn = wid & 3;       // main GEMM 2x4 wave grid
    floatx4 acc[4][4];
#pragma unroll
    for (int i = 0; i < 4; ++i)
#pragma unroll
        for (int j = 0; j < 4; ++j) acc[i][j] = (floatx4)(0.0f);

    const u16* hf2p = Hf2 + (size_t)(b * NTOK + mrow) * DD;

    // ---- K loop ----
    for (int kc = 0; kc < 8; ++kc) {
        const int k0 = kc * 64;
        const int kb = k0 + seg * 16;
        {   // stage A: h = relu(hf2 + s1 + px*c0 + py*c1), packed-f32 math
            uint4 hv = *(const uint4*)(hf2p + kb);
            uint4 hw = *(const uint4*)(hf2p + kb + 8);
            uint4 sv = *(const uint4*)(s1b + kb);
            uint4 sw2 = *(const uint4*)(s1b + kb + 8);
            uint4 av = *(const uint4*)(c0b + kb);
            uint4 aw = *(const uint4*)(c0b + kb + 8);
            uint4 bv = *(const uint4*)(c1b + kb);
            uint4 bw = *(const uint4*)(c1b + kb + 8);
            auto hp = [&](u32 h, u32 s, u32 ca, u32 cb) -> u32 {
                f32x2 v = up2(h) + up2(s);          // v_pk_add_f32
                v += px2 * up2(ca);                 // v_pk_fma_f32
                v += py2 * up2(cb);                 // v_pk_fma_f32
                v.x = fmaxf(v.x, 0.0f); v.y = fmaxf(v.y, 0.0f);
                return pkbf(v.x, v.y);              // v_cvt_pk_bf16_f32
            };
            uint4 o0 = make_uint4(hp(hv.x, sv.x, av.x, bv.x), hp(hv.y, sv.y, av.y, bv.y),
                                  hp(hv.z, sv.z, av.z, bv.z), hp(hv.w, sv.w, av.w, bv.w));
            uint4 o1 = make_uint4(hp(hw.x, sw2.x, aw.x, bw.x), hp(hw.y, sw2.y, aw.y, bw.y),
                                  hp(hw.z, sw2.z, aw.z, bw.z), hp(hw.w, sw2.w, aw.w, bw.w));
            *(uint4*)(Atile + mrow * 64 + (((seg * 2    ) ^ swA) << 3)) = o0;
            *(uint4*)(Atile + mrow * 64 + (((seg * 2 + 1) ^ swA) << 3)) = o1;
        }
        {   // stage B (W2T): c = tid>>1, 32 elems (R8 form: load+store tight)
            const int c = tid >> 1, sgB = tid & 1, swB = c & 7;
            const uint4* src = (const uint4*)(W2T + (size_t)c * DD + k0 + sgB * 32);
#pragma unroll
            for (int j = 0; j < 4; ++j)
                *(uint4*)(Btile + c * 64 + (((sgB * 4 + j) ^ swB) << 3)) = src[j];
        }
        __syncthreads();
#pragma unroll
        for (int ks = 0; ks < 2; ++ks) {
            const int ch = ks * 4 + quad;
            bf16x8 afr[4], bfr[4];
#pragma unroll
            for (int i = 0; i < 4; ++i) {
                int r = wm * 64 + i * 16 + lrow;
                afr[i] = *(const bf16x8*)(Atile + r * 64 + ((ch ^ (r & 7)) << 3));
            }
#pragma unroll
            for (int j = 0; j < 4; ++j) {
                int c = wn * 64 + j * 16 + lrow;
                bfr[j] = *(const bf16x8*)(Btile + c * 64 + ((ch ^ (c & 7)) << 3));
            }
#pragma unroll
            for (int i = 0; i < 4; ++i)
#pragma unroll
                for (int j = 0; j < 4; ++j)
                    acc[i][j] = __builtin_amdgcn_mfma_f32_16x16x32_bf16(afr[i], bfr[j], acc[i][j], 0, 0, 0);
        }
        __syncthreads();
    }

    // ---- epilogue: relu(acc+b2) -> gh bf16 halves -> layer-3 MFMA ----
    float b2v[4];
#pragma unroll
    for (int j = 0; j < 4; ++j) b2v[j] = b2[wn * 64 + j * 16 + lrow];

    const int smrow = wid * 16;                  // per-wave epilogue row block
    floatx4 acc3 = (floatx4)(0.0f);
#pragma unroll
    for (int half = 0; half < 2; ++half) {
        __syncthreads();
        if ((wn >> 1) == half) {
#pragma unroll
            for (int i = 0; i < 4; ++i)
#pragma unroll
                for (int j = 0; j < 4; ++j)
#pragma unroll
                    for (int r = 0; r < 4; ++r) {
                        int row = wm * 64 + i * 16 + quad * 4 + r;
                        int col = (wn & 1) * 64 + j * 16 + lrow;
                        gh[row * 136 + col] = f2bf(fmaxf(acc[i][j][r] + b2v[j], 0.0f));
                    }
        }
        __syncthreads();
#pragma unroll
        for (int ks = 0; ks < 4; ++ks) {
            bf16x8 gfrag = *(const bf16x8*)(gh + (smrow + lrow) * 136 + ks * 32 + quad * 8);
            bf16x8 wfrag = *(const bf16x8*)(w3t + lrow * 264 + half * 128 + ks * 32 + quad * 8);
            acc3 = __builtin_amdgcn_mfma_f32_16x16x32_bf16(gfrag, wfrag, acc3, 0, 0, 0);
        }
    }
    if (lrow < 4) {
        float bo = b3[lrow];
#pragma unroll
        for (int r = 0; r < 4; ++r) {
            int row = smrow + quad * 4 + r;
            out[(size_t)base_bn * 512 + row * 4 + lrow] = acc3[r] + bo;
        }
    }
}

// ---------------------------------------------------------------------------
extern "C" void kernel_launch(void* const* d_in, const int* in_sizes, int n_in,
                              void* d_out, int out_size, void* d_ws, size_t ws_size,
                              hipStream_t stream)
{
    const float* features  = (const float*)d_in[0];
    const float* positions = (const float*)d_in[1];
    const float* W1 = (const float*)d_in[2];
    const float* b1 = (const float*)d_in[3];
    const float* W2 = (const float*)d_in[4];
    const float* b2 = (const float*)d_in[5];
    const float* W3 = (const float*)d_in[6];
    const float* b3 = (const float*)d_in[7];
    float* out = (float*)d_out;

    char* ws = (char*)d_ws;
    u16* W2T  = (u16*)(ws);                 // 256*512*2 = 262144 B
    u16* Hf1b = (u16*)(ws + 262144);        // 1048576 B
    u16* Hf2  = (u16*)(ws + 1310720);       // 1048576 B (total 2.25 MB)

    prep_k<<<dim3(16, 8, 3), 512, 0, stream>>>(features, W1, W2, b1, Hf1b, Hf2, W2T);
    fused_main<<<dim3(8, 128), 512, 0, stream>>>(Hf1b, Hf2, W2T, W1, b2, W3, b3,
                                                 positions, out);
}

// Round 11
// 126.810 us; speedup vs baseline: 1.1170x; 1.0400x over previous
//
#include <hip/hip_runtime.h>
#include <hip/hip_bf16.h>

typedef unsigned short u16;
typedef unsigned int u32;
typedef __attribute__((ext_vector_type(8))) short bf16x8;
typedef __attribute__((ext_vector_type(4))) float floatx4;

__device__ __forceinline__ float bflo(u32 u){ union{u32 i; float f;}v; v.i=u<<16; return v.f; }
__device__ __forceinline__ float bfhi(u32 u){ union{u32 i; float f;}v; v.i=u&0xFFFF0000u; return v.f; }
__device__ __forceinline__ u16 f2bf(float f){
    union{float f;u32 i;}v; v.f=f; u32 r=v.i+0x7FFFu+((v.i>>16)&1u); return (u16)(r>>16);
}
__device__ __forceinline__ u32 pkbf(float a, float b){
    union { __hip_bfloat162 h; u32 u; } cv;
    cv.h = __float22bfloat162_rn(float2{a, b});
    return cv.u;
}

#define DD 512
#define NTOK 128

// ---------------------------------------------------------------------------
// prep_k: grid (16,8,3), 512 thr.  (R5-proven, unchanged)
// ---------------------------------------------------------------------------
__global__ __launch_bounds__(512) void prep_k(
    const float* __restrict__ features, const float* __restrict__ W1,
    const float* __restrict__ W2, const float* __restrict__ b1,
    u16* __restrict__ Hf1b, u16* __restrict__ Hf2, u16* __restrict__ W2T)
{
    const int z = blockIdx.z;
    const int tid = threadIdx.x;

    if (z == 2) {   // W2 transpose
        __shared__ u16 tile[32][33];
        const int tx = tid & 31, ty = tid >> 5;      // ty 0..15
        const int r0 = blockIdx.x * 32, c0 = blockIdx.y * 32;
#pragma unroll
        for (int i = 0; i < 2; ++i) {
            int r = ty + i * 16;
            tile[r][tx] = f2bf(W2[(size_t)(r0 + r) * 256 + (c0 + tx)]);
        }
        __syncthreads();
#pragma unroll
        for (int i = 0; i < 2; ++i) {
            int c = ty + i * 16;
            W2T[(size_t)(c0 + c) * 512 + (r0 + tx)] = tile[tx][c];
        }
        return;
    }

    const int bM = blockIdx.x, bN = blockIdx.y;
    u16* outp = z ? Hf2 : Hf1b;
    __shared__ __align__(16) u16 At[64 * 64];
    __shared__ __align__(16) u16 Btl[64 * 64];
    const int wid = tid >> 6, lane = tid & 63, lrow = lane & 15, quad = lane >> 4;
    const int wm = wid >> 1, wn = wid & 1;

    floatx4 acc[2];
    acc[0] = (floatx4)(0.0f); acc[1] = (floatx4)(0.0f);

    const int m = tid >> 3, seg = tid & 7, sw = m & 7;      // A staging map
    const int kr = tid >> 3, csB = tid & 7;                 // B staging map

    for (int kc = 0; kc < 8; ++kc) {
        const int k0 = kc * 64;
        {   // stage A: 8 fp32 -> 8 bf16, one uint4, XOR-swizzled
            const float4* src = (const float4*)(features + (size_t)(bM * 64 + m) * DD + k0 + seg * 8);
            float4 f0 = src[0], f1 = src[1];
            *(uint4*)(At + m * 64 + ((seg ^ sw) << 3)) =
                make_uint4(pkbf(f0.x, f0.y), pkbf(f0.z, f0.w), pkbf(f1.x, f1.y), pkbf(f1.z, f1.w));
        }
        {   // stage B from W1 rows (transpose-in-write, swizzled scalar b16)
            const float4* src = (const float4*)(W1 + (size_t)(z * 512 + k0 + kr) * DD + bN * 64 + csB * 8);
            float4 g0 = src[0], g1 = src[1];
            float f[8] = { g0.x, g0.y, g0.z, g0.w, g1.x, g1.y, g1.z, g1.w };
            const int chunkB = (kr >> 3), offB = kr & 7;
#pragma unroll
            for (int i = 0; i < 8; ++i) {
                int c = csB * 8 + i;                        // c & 7 == i
                Btl[c * 64 + ((chunkB ^ i) << 3) + offB] = f2bf(f[i]);
            }
        }
        __syncthreads();
#pragma unroll
        for (int ks = 0; ks < 2; ++ks) {
            const int ch = ks * 4 + quad;
            int r = wm * 16 + lrow;
            bf16x8 afr = *(const bf16x8*)(At + r * 64 + ((ch ^ (r & 7)) << 3));
#pragma unroll
            for (int j = 0; j < 2; ++j) {
                int c = wn * 32 + j * 16 + lrow;
                bf16x8 bfr = *(const bf16x8*)(Btl + c * 64 + ((ch ^ (c & 7)) << 3));
                acc[j] = __builtin_amdgcn_mfma_f32_16x16x32_bf16(afr, bfr, acc[j], 0, 0, 0);
            }
        }
        __syncthreads();
    }
#pragma unroll
    for (int j = 0; j < 2; ++j) {
        int col = bN * 64 + wn * 32 + j * 16 + lrow;
        float bb = z ? 0.0f : b1[col];
#pragma unroll
        for (int r = 0; r < 4; ++r) {
            int row = bM * 64 + wm * 16 + quad * 4 + r;
            outp[(size_t)row * DD + col] = f2bf(acc[j][r] + bb);
        }
    }
}

// ---------------------------------------------------------------------------
// Fused main — R8 frame (scalar H-build, VGPR=64, XCD-pinned grid) with B
// staging replaced by global_load_lds width=16 DMA (zero data VGPRs; R7
// proved the swizzle-inverted mapping correct; its +20-reg cost came from
// persistent pointer ARRAYS, collapsed here to one lane pointer since the
// source chunk swizzle (lane&7)^(lane>>3) is q-invariant). DMA issues at
// the top of kc so stage-A VALU hides the L2 latency; the compiler's
// vmcnt(0) drain at the barrier completes it.
// ---------------------------------------------------------------------------
__global__ __launch_bounds__(512) void fused_main(
    const u16* __restrict__ Hf1b, const u16* __restrict__ Hf2,
    const u16* __restrict__ W2T, const float* __restrict__ W1,
    const float* __restrict__ b2, const float* __restrict__ W3,
    const float* __restrict__ b3, const float* __restrict__ positions,
    float* __restrict__ out)
{
    const int b = blockIdx.x, n = blockIdx.y;     // b fastest -> XCD = b
    const int tid = threadIdx.x;
    const int base_bn = b * NTOK + n;
    const int wid = tid >> 6, lane = tid & 63, lrow = lane & 15, quad = lane >> 4;

    __shared__ __align__(16) u16 c0b[DD], c1b[DD], s1b[DD];  // bf16 coefs, 3 KB
    __shared__ __align__(16) u16 w3t[16 * 264];              // W3^T padded, 8.25 KB
    __shared__ __align__(16) char mbuf[49152];   // Atile 16K + Btile 32K | gh 34K
    u16* Atile = (u16*)mbuf;                     // [128][64] swizzled
    u16* Btile = (u16*)(mbuf + 16384);           // [256][64] swizzled
    u16* gh    = (u16*)mbuf;                     // [128][136] epilogue

    // ---- phase 0 ----
    {
        int k = tid;  // 512 threads == DD
        c0b[k] = f2bf(W1[(size_t)1024 * DD + k]);
        c1b[k] = f2bf(W1[(size_t)1025 * DD + k]);
        s1b[k] = Hf1b[(size_t)base_bn * DD + k];   // b1 already folded
    }
    {   // w3t: W3 (256x4 fp32) transposed, padded to 16 cols, bf16
        int c = tid & 15, kb2 = tid >> 4;          // kb2 0..31
        int k0w = kb2 * 8;
        u32 wv[4];
#pragma unroll
        for (int p = 0; p < 4; ++p) {
            int ka = k0w + p * 2;
            u16 va = (c < 4) ? f2bf(W3[ka * 4 + c])       : (u16)0;
            u16 vb = (c < 4) ? f2bf(W3[(ka + 1) * 4 + c]) : (u16)0;
            wv[p] = (u32)va | ((u32)vb << 16);
        }
        *(uint2*)(w3t + c * 264 + k0w)     = make_uint2(wv[0], wv[1]);
        *(uint2*)(w3t + c * 264 + k0w + 4) = make_uint2(wv[2], wv[3]);
    }
    const int mrow = tid >> 2, seg = tid & 3, swA = mrow & 7;
    float px, py;
    {
        float pnx = positions[(size_t)base_bn * 2 + 0];
        float pny = positions[(size_t)base_bn * 2 + 1];
        px = pnx - positions[(size_t)(b * NTOK + mrow) * 2 + 0];
        py = pny - positions[(size_t)(b * NTOK + mrow) * 2 + 1];
    }
    // B-DMA lane source pointer: lane covers row c = slot*8 + (lane>>3),
    // 16B chunk w = lane&7, stored at source chunk (w ^ (c&7)); c&7 == lane>>3,
    // so the offset is q-invariant -> single persistent pointer.
    const int csrc = lane >> 3, wsrc = lane & 7;
    const u16* bsrc_lane = W2T + csrc * DD + ((wsrc ^ csrc) << 3);
    __syncthreads();

    const int wm = wid >> 2, wn = wid & 3;       // main GEMM 2x4 wave grid
    floatx4 acc[4][4];
#pragma unroll
    for (int i = 0; i < 4; ++i)
#pragma unroll
        for (int j = 0; j < 4; ++j) acc[i][j] = (floatx4)(0.0f);

    const u16* hf2p = Hf2 + (size_t)(b * NTOK + mrow) * DD;

    // ---- K loop ----
    for (int kc = 0; kc < 8; ++kc) {
        const int k0 = kc * 64;
        // stage B via LDS-DMA first (zero data regs; latency hidden by stage-A)
#pragma unroll
        for (int q = 0; q < 4; ++q) {
            const int slot = wid * 4 + q;        // wave-uniform
            __builtin_amdgcn_global_load_lds(
                (const __attribute__((address_space(1))) u32*)(bsrc_lane + slot * 8 * DD + k0),
                (__attribute__((address_space(3))) u32*)(Btile + slot * 512), 16, 0, 0);
        }

        const int kb = k0 + seg * 16;
        {   // stage A: h = relu(hf2 + s1 + px*c0 + py*c1), 16 elems/thread
            uint4 hv = *(const uint4*)(hf2p + kb);
            uint4 hw = *(const uint4*)(hf2p + kb + 8);
            uint4 sv = *(const uint4*)(s1b + kb);
            uint4 sw2 = *(const uint4*)(s1b + kb + 8);
            uint4 av = *(const uint4*)(c0b + kb);
            uint4 aw = *(const uint4*)(c0b + kb + 8);
            uint4 bv = *(const uint4*)(c1b + kb);
            uint4 bw = *(const uint4*)(c1b + kb + 8);
            auto hp = [&](u32 h, u32 s, u32 ca, u32 cb) -> u32 {
                float h0 = bflo(h) + bflo(s) + px * bflo(ca) + py * bflo(cb);
                float h1 = bfhi(h) + bfhi(s) + px * bfhi(ca) + py * bfhi(cb);
                return pkbf(fmaxf(h0, 0.0f), fmaxf(h1, 0.0f));
            };
            uint4 o0 = make_uint4(hp(hv.x, sv.x, av.x, bv.x), hp(hv.y, sv.y, av.y, bv.y),
                                  hp(hv.z, sv.z, av.z, bv.z), hp(hv.w, sv.w, av.w, bv.w));
            uint4 o1 = make_uint4(hp(hw.x, sw2.x, aw.x, bw.x), hp(hw.y, sw2.y, aw.y, bw.y),
                                  hp(hw.z, sw2.z, aw.z, bw.z), hp(hw.w, sw2.w, aw.w, bw.w));
            *(uint4*)(Atile + mrow * 64 + (((seg * 2    ) ^ swA) << 3)) = o0;
            *(uint4*)(Atile + mrow * 64 + (((seg * 2 + 1) ^ swA) << 3)) = o1;
        }
        __syncthreads();   // vmcnt(0)+lgkmcnt(0) drain: Atile and B-DMA ready
#pragma unroll
        for (int ks = 0; ks < 2; ++ks) {
            const int ch = ks * 4 + quad;
            bf16x8 afr[4], bfr[4];
#pragma unroll
            for (int i = 0; i < 4; ++i) {
                int r = wm * 64 + i * 16 + lrow;
                afr[i] = *(const bf16x8*)(Atile + r * 64 + ((ch ^ (r & 7)) << 3));
            }
#pragma unroll
            for (int j = 0; j < 4; ++j) {
                int c = wn * 64 + j * 16 + lrow;
                bfr[j] = *(const bf16x8*)(Btile + c * 64 + ((ch ^ (c & 7)) << 3));
            }
#pragma unroll
            for (int i = 0; i < 4; ++i)
#pragma unroll
                for (int j = 0; j < 4; ++j)
                    acc[i][j] = __builtin_amdgcn_mfma_f32_16x16x32_bf16(afr[i], bfr[j], acc[i][j], 0, 0, 0);
        }
        __syncthreads();
    }

    // ---- epilogue: relu(acc+b2) -> gh bf16 halves -> layer-3 MFMA ----
    float b2v[4];
#pragma unroll
    for (int j = 0; j < 4; ++j) b2v[j] = b2[wn * 64 + j * 16 + lrow];

    const int smrow = wid * 16;                  // per-wave epilogue row block
    floatx4 acc3 = (floatx4)(0.0f);
#pragma unroll
    for (int half = 0; half < 2; ++half) {
        __syncthreads();
        if ((wn >> 1) == half) {
#pragma unroll
            for (int i = 0; i < 4; ++i)
#pragma unroll
                for (int j = 0; j < 4; ++j)
#pragma unroll
                    for (int r = 0; r < 4; ++r) {
                        int row = wm * 64 + i * 16 + quad * 4 + r;
                        int col = (wn & 1) * 64 + j * 16 + lrow;
                        gh[row * 136 + col] = f2bf(fmaxf(acc[i][j][r] + b2v[j], 0.0f));
                    }
        }
        __syncthreads();
#pragma unroll
        for (int ks = 0; ks < 4; ++ks) {
            bf16x8 gfrag = *(const bf16x8*)(gh + (smrow + lrow) * 136 + ks * 32 + quad * 8);
            bf16x8 wfrag = *(const bf16x8*)(w3t + lrow * 264 + half * 128 + ks * 32 + quad * 8);
            acc3 = __builtin_amdgcn_mfma_f32_16x16x32_bf16(gfrag, wfrag, acc3, 0, 0, 0);
        }
    }
    if (lrow < 4) {
        float bo = b3[lrow];
#pragma unroll
        for (int r = 0; r < 4; ++r) {
            int row = smrow + quad * 4 + r;
            out[(size_t)base_bn * 512 + row * 4 + lrow] = acc3[r] + bo;
        }
    }
}

// ---------------------------------------------------------------------------
extern "C" void kernel_launch(void* const* d_in, const int* in_sizes, int n_in,
                              void* d_out, int out_size, void* d_ws, size_t ws_size,
                              hipStream_t stream)
{
    const float* features  = (const float*)d_in[0];
    const float* positions = (const float*)d_in[1];
    const float* W1 = (const float*)d_in[2];
    const float* b1 = (const float*)d_in[3];
    const float* W2 = (const float*)d_in[4];
    const float* b2 = (const float*)d_in[5];
    const float* W3 = (const float*)d_in[6];
    const float* b3 = (const float*)d_in[7];
    float* out = (float*)d_out;

    char* ws = (char*)d_ws;
    u16* W2T  = (u16*)(ws);                 // 256*512*2 = 262144 B
    u16* Hf1b = (u16*)(ws + 262144);        // 1048576 B
    u16* Hf2  = (u16*)(ws + 1310720);       // 1048576 B (total 2.25 MB)

    prep_k<<<dim3(16, 8, 3), 512, 0, stream>>>(features, W1, W2, b1, Hf1b, Hf2, W2T);
    fused_main<<<dim3(8, 128), 512, 0, stream>>>(Hf1b, Hf2, W2T, W1, b2, W3, b3,
                                                 positions, out);
}